// Round 6
// baseline (1579.504 us; speedup 1.0000x reference)
//
#include <hip/hip_runtime.h>

#define N_NODES   50000
#define N_EDGES   1600000
#define N_FEAT    512
#define N_HID     128
#define NUM_GRAPHS 128
#define N_WAVES_GEMM 3125     // 50000/16 rows per wave

#define NBUCK 391             // ceil(50000/128) buckets of 128 dst nodes
#define EPB   6400            // edges per bin block
#define BIN_BLOCKS 250        // N_EDGES / EPB
#define PREP_DINV_BLOCKS 196  // ceil(50000/256)

typedef short bf16x8 __attribute__((ext_vector_type(8)));
typedef float f32x4  __attribute__((ext_vector_type(4)));

static __device__ __forceinline__ unsigned short f2bf(float f) {
  union { float f; unsigned int u; } v; v.f = f;
  unsigned int u = v.u;
  unsigned int r = (u + 0x7FFFu + ((u >> 16) & 1u)) >> 16;   // RNE
  return (unsigned short)r;
}
static __device__ __forceinline__ float bf2f(unsigned int bits16) {
  union { unsigned int u; float f; } v; v.u = bits16 << 16; return v.f;
}

// ---------------- init: zero cnt / pooled ----------------
__global__ void init_ws(int* __restrict__ cnt, int* __restrict__ pooled) {
  int i = blockIdx.x * 256 + threadIdx.x;
  if (i < N_NODES) cnt[i] = 0;
  if (i < NUM_GRAPHS * N_HID) pooled[i] = 0;
}

// ---------------- degree count over dst ----------------
__global__ void count_deg(const int* __restrict__ edge, int* __restrict__ cnt) {
  int e = blockIdx.x * 256 + threadIdx.x;
  if (e < N_EDGES) atomicAdd(&cnt[edge[N_EDGES + e]], 1);
}

// ------- prep: dinv + bucket sums (blocks 0..195) | wconv (blocks 196..451) -------
__global__ __launch_bounds__(256) void prep(const int* __restrict__ cnt,
                                            float* __restrict__ dinv,
                                            int* __restrict__ bucket_cnt,
                                            const float* __restrict__ W,
                                            unsigned short* __restrict__ wT) {
  if (blockIdx.x < PREP_DINV_BLOCKS) {
    __shared__ int red[256];
    int t = threadIdx.x;
    int node = blockIdx.x * 256 + t;
    int c = 0;
    if (node < N_NODES) {
      c = cnt[node];
      dinv[node] = rsqrtf((float)(c + 1));
    }
    red[t] = c;
    __syncthreads();
    for (int d = 64; d > 0; d >>= 1) {
      if ((t & 127) < d) red[t] += red[t + d];
      __syncthreads();
    }
    int b2 = blockIdx.x * 2;
    if (t == 0) bucket_cnt[b2] = red[0];
    if (t == 128 && b2 + 1 < NBUCK) bucket_cnt[b2 + 1] = red[128];
  } else {
    int i = (blockIdx.x - PREP_DINV_BLOCKS) * 256 + threadIdx.x;
    if (i < N_HID * N_FEAT) {
      int n = i >> 9, k = i & 511;
      wT[i] = f2bf(W[(size_t)k * N_HID + n]);
    }
  }
}

// ---------------- exclusive scan of bucket_cnt (391), 1 block ----------------
__global__ __launch_bounds__(256) void bucket_scan(const int* __restrict__ bucket_cnt,
                                                   int* __restrict__ bucket_base,
                                                   int* __restrict__ gcursor) {
  __shared__ int tsum[256];
  int t = threadIdx.x;
  int i0 = 2 * t, i1 = 2 * t + 1;
  int v0 = (i0 < NBUCK) ? bucket_cnt[i0] : 0;
  int v1 = (i1 < NBUCK) ? bucket_cnt[i1] : 0;
  tsum[t] = v0 + v1;
  __syncthreads();
  for (int d = 1; d < 256; d <<= 1) {
    int add = (t >= d) ? tsum[t - d] : 0;
    __syncthreads();
    tsum[t] += add;
    __syncthreads();
  }
  int excl = tsum[t] - (v0 + v1);
  if (i0 < NBUCK) { bucket_base[i0] = excl;      gcursor[i0] = excl; }
  if (i1 < NBUCK) { bucket_base[i1] = excl + v0; gcursor[i1] = excl + v0; }
}

// -------- bin_edges v2: LDS-staged bucket-sorted scatter, coalesced writes -------
// record: src | dst<<16  (both < 65536)
__global__ __launch_bounds__(256) void bin_edges(const int* __restrict__ edge,
                                                 int* __restrict__ gcursor,
                                                 unsigned int* __restrict__ brec) {
  __shared__ unsigned int recs[EPB];        // 25.6 KB
  __shared__ int lcnt[NBUCK], lbase[NBUCK], lscan[NBUCK], lcur[NBUCK];
  __shared__ int tsum[256];
  const int t = threadIdx.x;
  const int e0 = blockIdx.x * EPB;

  for (int b = t; b < NBUCK; b += 256) lcnt[b] = 0;
  __syncthreads();
  // pass 1: count buckets
  for (int e = e0 + t; e < e0 + EPB; e += 256)
    atomicAdd(&lcnt[edge[N_EDGES + e] >> 7], 1);
  __syncthreads();
  // local exclusive scan (391 entries, 2 per thread)
  int i0 = 2 * t, i1 = 2 * t + 1;
  int v0 = (i0 < NBUCK) ? lcnt[i0] : 0;
  int v1 = (i1 < NBUCK) ? lcnt[i1] : 0;
  tsum[t] = v0 + v1;
  __syncthreads();
  for (int d = 1; d < 256; d <<= 1) {
    int add = (t >= d) ? tsum[t - d] : 0;
    __syncthreads();
    tsum[t] += add;
    __syncthreads();
  }
  int excl = tsum[t] - (v0 + v1);
  if (i0 < NBUCK) lscan[i0] = excl;
  if (i1 < NBUCK) lscan[i1] = excl + v0;
  // reserve global space + zero cursors
  for (int b = t; b < NBUCK; b += 256) {
    int c = lcnt[b];
    lbase[b] = c ? atomicAdd(&gcursor[b], c) : 0;
    lcur[b] = 0;
  }
  __syncthreads();
  // pass 2: place into LDS at bucket-sorted local position
  for (int e = e0 + t; e < e0 + EPB; e += 256) {
    unsigned int s = (unsigned int)edge[e];
    unsigned int d = (unsigned int)edge[N_EDGES + e];
    int b = d >> 7;
    int pos = lscan[b] + atomicAdd(&lcur[b], 1);
    recs[pos] = s | (d << 16);
  }
  __syncthreads();
  // pass 3: dense coalesced write-out
  for (int i = t; i < EPB; i += 256) {
    unsigned int r = recs[i];
    int b = r >> 23;
    brec[lbase[b] + (i - lscan[b])] = r;
  }
}

// ---------------- GEMM: h'(bf16)[N,128] = dinv * (x[N,512] @ W1) via MFMA --------
__global__ __launch_bounds__(256) void gemm_mfma(const float* __restrict__ x,
                                                 const unsigned short* __restrict__ wT,
                                                 const float* __restrict__ dinv,
                                                 unsigned short* __restrict__ h) {
  const int wave = (blockIdx.x * 256 + threadIdx.x) >> 6;
  if (wave >= N_WAVES_GEMM) return;
  const int lane = threadIdx.x & 63;
  const int row0 = wave * 16;
  const int arow = row0 + (lane & 15);
  const int kbase = (lane >> 4) * 8;

  f32x4 acc[8];
#pragma unroll
  for (int i = 0; i < 8; i++) acc[i] = (f32x4){0.f, 0.f, 0.f, 0.f};

  for (int k0 = 0; k0 < N_FEAT; k0 += 32) {
    const float* ap = x + (size_t)arow * N_FEAT + k0 + kbase;
    float4 a0 = *(const float4*)ap;
    float4 a1 = *(const float4*)(ap + 4);
    bf16x8 af;
    af[0] = (short)f2bf(a0.x); af[1] = (short)f2bf(a0.y);
    af[2] = (short)f2bf(a0.z); af[3] = (short)f2bf(a0.w);
    af[4] = (short)f2bf(a1.x); af[5] = (short)f2bf(a1.y);
    af[6] = (short)f2bf(a1.z); af[7] = (short)f2bf(a1.w);

#pragma unroll
    for (int ct = 0; ct < 8; ct++) {
      const bf16x8 bf = *(const bf16x8*)(wT + (size_t)(ct * 16 + (lane & 15)) * N_FEAT
                                            + k0 + kbase);
      acc[ct] = __builtin_amdgcn_mfma_f32_16x16x32_bf16(af, bf, acc[ct], 0, 0, 0);
    }
  }

  float dvv[4];
#pragma unroll
  for (int r = 0; r < 4; r++) dvv[r] = dinv[row0 + (lane >> 4) * 4 + r];
#pragma unroll
  for (int ct = 0; ct < 8; ct++) {
#pragma unroll
    for (int r = 0; r < 4; r++) {
      int row = row0 + (lane >> 4) * 4 + r;
      int col = ct * 16 + (lane & 15);
      h[(size_t)row * N_HID + col] = f2bf(acc[ct][r] * dvv[r]);
    }
  }
}

// -------- bucket_agg: per-bucket LDS fp32 accumulation via ds_add_f32 ----------
// 1 block = 1 bucket (128 dst nodes), 512 threads = 8 waves, 64 KB LDS acc.
__global__ __launch_bounds__(512) void bucket_agg(
    const unsigned short* __restrict__ h, const unsigned int* __restrict__ brec,
    const int* __restrict__ bucket_base, const int* __restrict__ bucket_cnt,
    const float* __restrict__ dinv, const float* __restrict__ b1,
    const int* __restrict__ batch, int* __restrict__ pooled) {
  __shared__ float acc[128][N_HID];      // exactly 64 KB
  const int t = threadIdx.x;
  const int wv = t >> 6;
  const int lane = t & 63;
  const int f2 = lane * 2;
  const int bb = blockIdx.x;
  const int nbase = bb << 7;

  {
    float4* a4 = (float4*)(&acc[0][0]);
    for (int i = t; i < 128 * N_HID / 4; i += 512) a4[i] = (float4){0.f, 0.f, 0.f, 0.f};
  }
  __syncthreads();

  const int base = bucket_base[bb];
  const int nb = bucket_cnt[bb];

  // edge accumulation: strips of 512 (64 per wave); sentinel = 0xFFFFFFFF
  for (int s0 = wv * 64; s0 < nb; s0 += 512) {
    int idx = s0 + lane;
    unsigned int rl = (idx < nb) ? brec[base + idx] : 0xFFFFFFFFu;
#pragma unroll
    for (int u8 = 0; u8 < 64; u8 += 8) {
      unsigned int rr[8], qq[8];
#pragma unroll
      for (int u = 0; u < 8; u++) rr[u] = (unsigned int)__shfl((int)rl, u8 + u);
#pragma unroll
      for (int u = 0; u < 8; u++) {
        unsigned int srow = (rr[u] != 0xFFFFFFFFu) ? (rr[u] & 0xFFFFu) : 0u;
        qq[u] = *(const unsigned int*)(h + (size_t)srow * N_HID + f2);
      }
#pragma unroll
      for (int u = 0; u < 8; u++) {
        if (rr[u] != 0xFFFFFFFFu) {                    // wave-uniform branch
          int dl = (int)((rr[u] >> 16) & 127u);
          unsafeAtomicAdd(&acc[dl][f2],     bf2f(qq[u] & 0xFFFFu));
          unsafeAtomicAdd(&acc[dl][f2 + 1], bf2f(qq[u] >> 16));
        }
      }
    }
  }
  __syncthreads();

  // finalize: self-loop + dinv[dst] + bias + relu + per-graph max in registers
  const float bb0 = b1[f2], bb1 = b1[f2 + 1];
  int ga = -1, gb = -1;
  float m0a = 0.f, m1a = 0.f, m0b = 0.f, m1b = 0.f;   // relu'd values are >= 0
#pragma unroll 4
  for (int k = 0; k < 16; k++) {
    int dl = wv * 16 + k;
    int node = nbase + dl;
    if (node < N_NODES) {                              // wave-uniform
      unsigned int p = *(const unsigned int*)(h + (size_t)node * N_HID + f2);
      float dv = dinv[node];
      float v0 = fmaxf(fmaf(acc[dl][f2]     + bf2f(p & 0xFFFFu), dv, bb0), 0.f);
      float v1 = fmaxf(fmaf(acc[dl][f2 + 1] + bf2f(p >> 16),     dv, bb1), 0.f);
      int g = batch[node];                             // wave-uniform value
      if (ga < 0) ga = g;
      if (g == ga) { m0a = fmaxf(m0a, v0); m1a = fmaxf(m1a, v1); }
      else         { gb = g; m0b = fmaxf(m0b, v0); m1b = fmaxf(m1b, v1); }
    }
  }
  if (ga >= 0) {
    atomicMax(&pooled[ga * N_HID + f2],     __float_as_int(m0a));
    atomicMax(&pooled[ga * N_HID + f2 + 1], __float_as_int(m1a));
  }
  if (gb >= 0) {
    atomicMax(&pooled[gb * N_HID + f2],     __float_as_int(m0b));
    atomicMax(&pooled[gb * N_HID + f2 + 1], __float_as_int(m1b));
  }
}

// ---------------- head: logits + log_softmax ----------------
__global__ __launch_bounds__(128) void head_kernel(const int* __restrict__ pooled,
                                                   const float* __restrict__ W2,
                                                   const float* __restrict__ b2,
                                                   float* __restrict__ out) {
  __shared__ float sW[N_HID * 2];
  int t = threadIdx.x;
  sW[t] = W2[t];
  sW[t + 128] = W2[t + 128];
  __syncthreads();
  float l0 = b2[0], l1 = b2[1];
  for (int f = 0; f < N_HID; f++) {
    float pv = __int_as_float(pooled[t * N_HID + f]);
    l0 = fmaf(pv, sW[f * 2 + 0], l0);
    l1 = fmaf(pv, sW[f * 2 + 1], l1);
  }
  float m = fmaxf(l0, l1);
  float lse = m + logf(expf(l0 - m) + expf(l1 - m));
  out[t * 2 + 0] = l0 - lse;
  out[t * 2 + 1] = l1 - lse;
}

extern "C" void kernel_launch(void* const* d_in, const int* in_sizes, int n_in,
                              void* d_out, int out_size, void* d_ws, size_t ws_size,
                              hipStream_t stream) {
  const float* x   = (const float*)d_in[0];
  const float* W1  = (const float*)d_in[1];
  const float* b1  = (const float*)d_in[2];
  const float* W2  = (const float*)d_in[3];
  const float* b2  = (const float*)d_in[4];
  const int* edge  = (const int*)d_in[5];
  const int* batch = (const int*)d_in[6];
  float* out = (float*)d_out;

  char* ws = (char*)d_ws;
  int*   cnt         = (int*)(ws + 0);          // 200 KB
  float* dinv        = (float*)(ws + 200704);   // 200 KB
  int*   pooled      = (int*)(ws + 401408);     // 64 KB
  int*   bucket_cnt  = (int*)(ws + 466944);     // 2 KB
  int*   bucket_base = (int*)(ws + 468992);     // 2 KB
  int*   gcursor     = (int*)(ws + 471040);     // 2 KB
  unsigned int* brec = (unsigned int*)(ws + 473088);     // 6.4 MB
  unsigned short* h  = (unsigned short*)(ws + 6873088);  // 12.8 MB
  unsigned short* wT = (unsigned short*)(ws + 19673088); // 128 KB

  init_ws<<<196, 256, 0, stream>>>(cnt, pooled);
  count_deg<<<N_EDGES / 256, 256, 0, stream>>>(edge, cnt);
  prep<<<PREP_DINV_BLOCKS + 256, 256, 0, stream>>>(cnt, dinv, bucket_cnt, W1, wT);
  bucket_scan<<<1, 256, 0, stream>>>(bucket_cnt, bucket_base, gcursor);
  bin_edges<<<BIN_BLOCKS, 256, 0, stream>>>(edge, gcursor, brec);
  gemm_mfma<<<(N_WAVES_GEMM + 3) / 4, 256, 0, stream>>>(x, wT, dinv, h);
  bucket_agg<<<NBUCK, 512, 0, stream>>>(h, brec, bucket_base, bucket_cnt, dinv, b1, batch, pooled);
  head_kernel<<<1, 128, 0, stream>>>(pooled, W2, b2, out);
}

// Round 7
// 293.215 us; speedup vs baseline: 5.3868x; 5.3868x over previous
//
#include <hip/hip_runtime.h>

#define N_NODES   50000
#define N_EDGES   1600000
#define N_FEAT    512
#define N_HID     128
#define NUM_GRAPHS 128
#define N_WAVES_GEMM 3125     // 50000/16 rows per wave

#define NBUCK 391             // ceil(50000/128) buckets of 128 dst nodes
#define EPB   6400            // edges per bin block
#define BIN_BLOCKS 250        // N_EDGES / EPB
#define BCAP  5120            // raw bucket capacity in LDS
#define PREP_DINV_BLOCKS 196  // ceil(50000/256)

typedef short bf16x8 __attribute__((ext_vector_type(8)));
typedef float f32x4  __attribute__((ext_vector_type(4)));

static __device__ __forceinline__ unsigned short f2bf(float f) {
  union { float f; unsigned int u; } v; v.f = f;
  unsigned int u = v.u;
  unsigned int r = (u + 0x7FFFu + ((u >> 16) & 1u)) >> 16;   // RNE
  return (unsigned short)r;
}
static __device__ __forceinline__ float bfl(unsigned int w) {   // low bf16 of word
  union { unsigned int u; float f; } v; v.u = w << 16; return v.f;
}
static __device__ __forceinline__ float bfh(unsigned int w) {   // high bf16 of word
  union { unsigned int u; float f; } v; v.u = w & 0xFFFF0000u; return v.f;
}

// ---------------- init: zero cnt / pooled ----------------
__global__ void init_ws(int* __restrict__ cnt, int* __restrict__ pooled) {
  int i = blockIdx.x * 256 + threadIdx.x;
  if (i < N_NODES) cnt[i] = 0;
  if (i < NUM_GRAPHS * N_HID) pooled[i] = 0;
}

// ---------------- degree count over dst ----------------
__global__ void count_deg(const int* __restrict__ edge, int* __restrict__ cnt) {
  int e = blockIdx.x * 256 + threadIdx.x;
  if (e < N_EDGES) atomicAdd(&cnt[edge[N_EDGES + e]], 1);
}

// -- prep: dinv + raw/padded bucket sums (blocks 0..195) | wconv (196..451) --
__global__ __launch_bounds__(256) void prep(const int* __restrict__ cnt,
                                            float* __restrict__ dinv,
                                            int* __restrict__ braw,
                                            int* __restrict__ bpad,
                                            const float* __restrict__ W,
                                            unsigned short* __restrict__ wT) {
  if (blockIdx.x < PREP_DINV_BLOCKS) {
    __shared__ int red[256], redp[256];
    int t = threadIdx.x;
    int node = blockIdx.x * 256 + t;
    int c = 0;
    if (node < N_NODES) {
      c = cnt[node];
      dinv[node] = rsqrtf((float)(c + 1));
    }
    red[t] = c;
    redp[t] = (c + 3) & ~3;
    __syncthreads();
    for (int d = 64; d > 0; d >>= 1) {
      if ((t & 127) < d) { red[t] += red[t + d]; redp[t] += redp[t + d]; }
      __syncthreads();
    }
    int b2 = blockIdx.x * 2;
    if (t == 0)   { braw[b2] = red[0];   bpad[b2] = redp[0]; }
    if (t == 128 && b2 + 1 < NBUCK) { braw[b2 + 1] = red[128]; bpad[b2 + 1] = redp[128]; }
  } else {
    int i = (blockIdx.x - PREP_DINV_BLOCKS) * 256 + threadIdx.x;
    if (i < N_HID * N_FEAT) {
      int n = i >> 9, k = i & 511;
      wT[i] = f2bf(W[(size_t)k * N_HID + n]);
    }
  }
}

// ------ dual exclusive scans (raw -> rbase/gcursor, padded -> pbase), 1 block ------
__global__ __launch_bounds__(256) void bucket_scan(const int* __restrict__ braw,
                                                   const int* __restrict__ bpad,
                                                   int* __restrict__ rbase,
                                                   int* __restrict__ gcursor,
                                                   int* __restrict__ pbase) {
  __shared__ int tsum[256];
  int t = threadIdx.x;
  int i0 = 2 * t, i1 = 2 * t + 1;
  // raw scan
  {
    int v0 = (i0 < NBUCK) ? braw[i0] : 0;
    int v1 = (i1 < NBUCK) ? braw[i1] : 0;
    tsum[t] = v0 + v1;
    __syncthreads();
    for (int d = 1; d < 256; d <<= 1) {
      int add = (t >= d) ? tsum[t - d] : 0;
      __syncthreads();
      tsum[t] += add;
      __syncthreads();
    }
    int excl = tsum[t] - (v0 + v1);
    if (i0 < NBUCK) { rbase[i0] = excl;      gcursor[i0] = excl; }
    if (i1 < NBUCK) { rbase[i1] = excl + v0; gcursor[i1] = excl + v0; }
    __syncthreads();
  }
  // padded scan
  {
    int v0 = (i0 < NBUCK) ? bpad[i0] : 0;
    int v1 = (i1 < NBUCK) ? bpad[i1] : 0;
    tsum[t] = v0 + v1;
    __syncthreads();
    for (int d = 1; d < 256; d <<= 1) {
      int add = (t >= d) ? tsum[t - d] : 0;
      __syncthreads();
      tsum[t] += add;
      __syncthreads();
    }
    int excl = tsum[t] - (v0 + v1);
    if (i0 < NBUCK) pbase[i0] = excl;
    if (i1 < NBUCK) pbase[i1] = excl + v0;
  }
}

// -------- bin_edges: LDS-staged bucket-sorted scatter, coalesced writes ----------
// record: src | dst<<16
__global__ __launch_bounds__(256) void bin_edges(const int* __restrict__ edge,
                                                 int* __restrict__ gcursor,
                                                 unsigned int* __restrict__ brec) {
  __shared__ unsigned int recs[EPB];        // 25.6 KB
  __shared__ int lcnt[NBUCK], lbase[NBUCK], lscan[NBUCK], lcur[NBUCK];
  __shared__ int tsum[256];
  const int t = threadIdx.x;
  const int e0 = blockIdx.x * EPB;

  for (int b = t; b < NBUCK; b += 256) lcnt[b] = 0;
  __syncthreads();
  for (int e = e0 + t; e < e0 + EPB; e += 256)
    atomicAdd(&lcnt[edge[N_EDGES + e] >> 7], 1);
  __syncthreads();
  int i0 = 2 * t, i1 = 2 * t + 1;
  int v0 = (i0 < NBUCK) ? lcnt[i0] : 0;
  int v1 = (i1 < NBUCK) ? lcnt[i1] : 0;
  tsum[t] = v0 + v1;
  __syncthreads();
  for (int d = 1; d < 256; d <<= 1) {
    int add = (t >= d) ? tsum[t - d] : 0;
    __syncthreads();
    tsum[t] += add;
    __syncthreads();
  }
  int excl = tsum[t] - (v0 + v1);
  if (i0 < NBUCK) lscan[i0] = excl;
  if (i1 < NBUCK) lscan[i1] = excl + v0;
  for (int b = t; b < NBUCK; b += 256) {
    int c = lcnt[b];
    lbase[b] = c ? atomicAdd(&gcursor[b], c) : 0;
    lcur[b] = 0;
  }
  __syncthreads();
  for (int e = e0 + t; e < e0 + EPB; e += 256) {
    unsigned int s = (unsigned int)edge[e];
    unsigned int d = (unsigned int)edge[N_EDGES + e];
    int b = d >> 7;
    int pos = lscan[b] + atomicAdd(&lcur[b], 1);
    recs[pos] = s | (d << 16);
  }
  __syncthreads();
  for (int i = t; i < EPB; i += 256) {
    unsigned int r = recs[i];
    int b = r >> 23;
    brec[lbase[b] + (i - lscan[b])] = r;
  }
}

// ---- sort_bucket: per-bucket counting sort by dst_local -> padded CSR sedge ----
// pads (to x4 per node) point at sentinel row N_NODES (zeros)
__global__ __launch_bounds__(256) void sort_bucket(const unsigned int* __restrict__ brec,
                                                   const int* __restrict__ rbase,
                                                   const int* __restrict__ braw,
                                                   const int* __restrict__ pbase,
                                                   int* __restrict__ sedge,
                                                   int* __restrict__ offs,
                                                   unsigned short* __restrict__ h) {
  __shared__ int recs[BCAP];           // 20 KB
  __shared__ int bcnt[128], poff[128], cur[128], scn[128];
  const int t = threadIdx.x;
  const int b = blockIdx.x;
  const int rb = rbase[b];
  const int pb = pbase[b];
  int nb = braw[b];
  if (nb > BCAP) nb = BCAP;

  // zero sentinel row h[N_NODES] once
  if (b == 0 && t < 64) ((unsigned int*)(h + (size_t)N_NODES * N_HID))[t] = 0u;

  for (int i = t; i < nb; i += 256) recs[i] = (int)brec[rb + i];
  if (t < 128) bcnt[t] = 0;
  __syncthreads();
  for (int i = t; i < nb; i += 256)
    atomicAdd(&bcnt[(recs[i] >> 16) & 127], 1);
  __syncthreads();
  int pc = 0;
  if (t < 128) { pc = (bcnt[t] + 3) & ~3; scn[t] = pc; }
  __syncthreads();
  for (int d = 1; d < 128; d <<= 1) {
    int add = (t >= d && t < 128) ? scn[t - d] : 0;
    __syncthreads();
    if (t < 128) scn[t] += add;
    __syncthreads();
  }
  if (t < 128) {
    poff[t] = scn[t] - pc;
    cur[t] = 0;
    int node = b * 128 + t;
    if (node < N_NODES) offs[node] = pb + poff[t];
  }
  __syncthreads();
  // scatter real edges
  for (int i = t; i < nb; i += 256) {
    int r = recs[i];
    int dl = (r >> 16) & 127;
    int pos = atomicAdd(&cur[dl], 1);
    sedge[pb + poff[dl] + pos] = r & 0xFFFF;
  }
  __syncthreads();
  // fill pads with sentinel
  if (t < 128) {
    int c = bcnt[t], p = (c + 3) & ~3;
    for (int k = c; k < p; k++) sedge[pb + poff[t] + k] = N_NODES;
  }
}

// ---------------- GEMM: h'(bf16)[N,128] = dinv * (x[N,512] @ W1) via MFMA --------
__global__ __launch_bounds__(256) void gemm_mfma(const float* __restrict__ x,
                                                 const unsigned short* __restrict__ wT,
                                                 const float* __restrict__ dinv,
                                                 unsigned short* __restrict__ h) {
  const int wave = (blockIdx.x * 256 + threadIdx.x) >> 6;
  if (wave >= N_WAVES_GEMM) return;
  const int lane = threadIdx.x & 63;
  const int row0 = wave * 16;
  const int arow = row0 + (lane & 15);
  const int kbase = (lane >> 4) * 8;

  f32x4 acc[8];
#pragma unroll
  for (int i = 0; i < 8; i++) acc[i] = (f32x4){0.f, 0.f, 0.f, 0.f};

  for (int k0 = 0; k0 < N_FEAT; k0 += 32) {
    const float* ap = x + (size_t)arow * N_FEAT + k0 + kbase;
    float4 a0 = *(const float4*)ap;
    float4 a1 = *(const float4*)(ap + 4);
    bf16x8 af;
    af[0] = (short)f2bf(a0.x); af[1] = (short)f2bf(a0.y);
    af[2] = (short)f2bf(a0.z); af[3] = (short)f2bf(a0.w);
    af[4] = (short)f2bf(a1.x); af[5] = (short)f2bf(a1.y);
    af[6] = (short)f2bf(a1.z); af[7] = (short)f2bf(a1.w);

#pragma unroll
    for (int ct = 0; ct < 8; ct++) {
      const bf16x8 bf = *(const bf16x8*)(wT + (size_t)(ct * 16 + (lane & 15)) * N_FEAT
                                            + k0 + kbase);
      acc[ct] = __builtin_amdgcn_mfma_f32_16x16x32_bf16(af, bf, acc[ct], 0, 0, 0);
    }
  }

  float dvv[4];
#pragma unroll
  for (int r = 0; r < 4; r++) dvv[r] = dinv[row0 + (lane >> 4) * 4 + r];
#pragma unroll
  for (int ct = 0; ct < 8; ct++) {
#pragma unroll
    for (int r = 0; r < 4; r++) {
      int row = row0 + (lane >> 4) * 4 + r;
      int col = ct * 16 + (lane & 15);
      h[(size_t)row * N_HID + col] = f2bf(acc[ct][r] * dvv[r]);
    }
  }
}

// ---- aggregate: CSR per node, dwordx4 gather (4 edges/instr), reg accumulators ----
// 512 threads = 8 waves = 8 nodes. lane: q=lane>>4 (edge slot), fs=lane&15 (16B feat slice)
__global__ __launch_bounds__(512) void aggregate_pool(
    const unsigned short* __restrict__ h, const int* __restrict__ sedge,
    const float* __restrict__ dinv, const int* __restrict__ cnt,
    const int* __restrict__ offs, const float* __restrict__ b1,
    const int* __restrict__ batch, int* __restrict__ pooled) {
  __shared__ float vsh[8][128];
  __shared__ int gsh[8];
  const int wv = threadIdx.x >> 6;
  const int lane = threadIdx.x & 63;
  const int q = lane >> 4;
  const int fs8 = (lane & 15) * 8;
  const int node = blockIdx.x * 8 + wv;       // 6250*8 == 50000

  float a0 = 0.f, a1 = 0.f, a2 = 0.f, a3 = 0.f, a4 = 0.f, a5 = 0.f, a6 = 0.f, a7 = 0.f;

  // self loop: only q==0 contributes (avoid 4x after reduce)
  if (q == 0) {
    uint4 w = *(const uint4*)(h + (size_t)node * N_HID + fs8);
    a0 += bfl(w.x); a1 += bfh(w.x); a2 += bfl(w.y); a3 += bfh(w.y);
    a4 += bfl(w.z); a5 += bfh(w.z); a6 += bfl(w.w); a7 += bfh(w.w);
  }

  const int base = offs[node];
  const int n4 = (cnt[node] + 3) & ~3;        // pads are sentinel zero-rows
#pragma unroll 2
  for (int j = 0; j < n4; j += 4) {
    int src = sedge[base + j + q];
    uint4 w = *(const uint4*)(h + (size_t)src * N_HID + fs8);
    a0 += bfl(w.x); a1 += bfh(w.x); a2 += bfl(w.y); a3 += bfh(w.y);
    a4 += bfl(w.z); a5 += bfh(w.z); a6 += bfl(w.w); a7 += bfh(w.w);
  }

  // reduce the 4 edge-slots (lanes differing in bits 4,5)
  a0 += __shfl_xor(a0, 16, 64); a1 += __shfl_xor(a1, 16, 64);
  a2 += __shfl_xor(a2, 16, 64); a3 += __shfl_xor(a3, 16, 64);
  a4 += __shfl_xor(a4, 16, 64); a5 += __shfl_xor(a5, 16, 64);
  a6 += __shfl_xor(a6, 16, 64); a7 += __shfl_xor(a7, 16, 64);
  a0 += __shfl_xor(a0, 32, 64); a1 += __shfl_xor(a1, 32, 64);
  a2 += __shfl_xor(a2, 32, 64); a3 += __shfl_xor(a3, 32, 64);
  a4 += __shfl_xor(a4, 32, 64); a5 += __shfl_xor(a5, 32, 64);
  a6 += __shfl_xor(a6, 32, 64); a7 += __shfl_xor(a7, 32, 64);

  const int g = batch[node];
  if (lane == 0) gsh[wv] = g;
  if (q == 0) {
    float dv = dinv[node];
    float4 ba = *(const float4*)(b1 + fs8);
    float4 bb = *(const float4*)(b1 + fs8 + 4);
    float4 v0, v1;
    v0.x = fmaxf(fmaf(a0, dv, ba.x), 0.f); v0.y = fmaxf(fmaf(a1, dv, ba.y), 0.f);
    v0.z = fmaxf(fmaf(a2, dv, ba.z), 0.f); v0.w = fmaxf(fmaf(a3, dv, ba.w), 0.f);
    v1.x = fmaxf(fmaf(a4, dv, bb.x), 0.f); v1.y = fmaxf(fmaf(a5, dv, bb.y), 0.f);
    v1.z = fmaxf(fmaf(a6, dv, bb.z), 0.f); v1.w = fmaxf(fmaf(a7, dv, bb.w), 0.f);
    *(float4*)(&vsh[wv][fs8]) = v0;
    *(float4*)(&vsh[wv][fs8 + 4]) = v1;
  }
  __syncthreads();
  int gprev = (wv > 0) ? gsh[wv - 1] : -1;
  if (g != gprev && q == 0) {                 // leader wave's 16 lanes
    float m[8];
#pragma unroll
    for (int j = 0; j < 8; j++) m[j] = vsh[wv][fs8 + j];
    for (int r = wv + 1; r < 8 && gsh[r] == g; r++)
#pragma unroll
      for (int j = 0; j < 8; j++) m[j] = fmaxf(m[j], vsh[r][fs8 + j]);
#pragma unroll
    for (int j = 0; j < 8; j++)
      atomicMax(&pooled[g * N_HID + fs8 + j], __float_as_int(m[j]));
  }
}

// ---------------- head: logits + log_softmax ----------------
__global__ __launch_bounds__(128) void head_kernel(const int* __restrict__ pooled,
                                                   const float* __restrict__ W2,
                                                   const float* __restrict__ b2,
                                                   float* __restrict__ out) {
  __shared__ float sW[N_HID * 2];
  int t = threadIdx.x;
  sW[t] = W2[t];
  sW[t + 128] = W2[t + 128];
  __syncthreads();
  float l0 = b2[0], l1 = b2[1];
  for (int f = 0; f < N_HID; f++) {
    float pv = __int_as_float(pooled[t * N_HID + f]);
    l0 = fmaf(pv, sW[f * 2 + 0], l0);
    l1 = fmaf(pv, sW[f * 2 + 1], l1);
  }
  float m = fmaxf(l0, l1);
  float lse = m + logf(expf(l0 - m) + expf(l1 - m));
  out[t * 2 + 0] = l0 - lse;
  out[t * 2 + 1] = l1 - lse;
}

extern "C" void kernel_launch(void* const* d_in, const int* in_sizes, int n_in,
                              void* d_out, int out_size, void* d_ws, size_t ws_size,
                              hipStream_t stream) {
  const float* x   = (const float*)d_in[0];
  const float* W1  = (const float*)d_in[1];
  const float* b1  = (const float*)d_in[2];
  const float* W2  = (const float*)d_in[3];
  const float* b2  = (const float*)d_in[4];
  const int* edge  = (const int*)d_in[5];
  const int* batch = (const int*)d_in[6];
  float* out = (float*)d_out;

  char* ws = (char*)d_ws;
  int*   cnt    = (int*)(ws + 0);          // 200 KB
  int*   offs   = (int*)(ws + 200704);     // 200 KB
  float* dinv   = (float*)(ws + 401408);   // 200 KB
  int*   pooled = (int*)(ws + 602112);     // 64 KB
  int*   braw   = (int*)(ws + 667648);     // 2 KB
  int*   bpad   = (int*)(ws + 669696);     // 2 KB
  int*   rbase  = (int*)(ws + 671744);     // 2 KB
  int*   gcursor= (int*)(ws + 673792);     // 2 KB
  int*   pbase  = (int*)(ws + 675840);     // 2 KB
  int*   sedge  = (int*)(ws + 677888);     // 7.0 MB (padded CSR, <= 1.75M ints)
  unsigned short* h = (unsigned short*)(ws + 7677952);   // 12.8 MB (50001 rows)
  unsigned int* brec = (unsigned int*)(ws + 7677952);    // aliases h (dead before gemm)
  unsigned short* wT = (unsigned short*)(ws + 20478464); // 128 KB

  init_ws<<<196, 256, 0, stream>>>(cnt, pooled);
  count_deg<<<N_EDGES / 256, 256, 0, stream>>>(edge, cnt);
  prep<<<PREP_DINV_BLOCKS + 256, 256, 0, stream>>>(cnt, dinv, braw, bpad, W1, wT);
  bucket_scan<<<1, 256, 0, stream>>>(braw, bpad, rbase, gcursor, pbase);
  bin_edges<<<BIN_BLOCKS, 256, 0, stream>>>(edge, gcursor, brec);
  sort_bucket<<<NBUCK, 256, 0, stream>>>(brec, rbase, braw, pbase, sedge, offs, h);
  gemm_mfma<<<(N_WAVES_GEMM + 3) / 4, 256, 0, stream>>>(x, wT, dinv, h);
  aggregate_pool<<<N_NODES / 8, 512, 0, stream>>>(h, sedge, dinv, cnt, offs, b1, batch, pooled);
  head_kernel<<<1, 128, 0, stream>>>(pooled, W2, b2, out);
}